// Round 2
// baseline (198.590 us; speedup 1.0000x reference)
//
#include <hip/hip_runtime.h>
#include <stdint.h>

// Problem constants (B=256, T=512) — all float tensors are FLOAT32 (per reference).
#define NTOK (256 * 512)
#define DDIM 88     // data_dim (tones)
#define HDIM 16     // hidden states
#define NDIM 48     // nn_dim
#define CDIM 176    // nn_channels * data_dim

// One thread per token. Weights staged to LDS once per block; all hot-loop
// weight reads are wave-uniform LDS broadcasts (conflict-free).
__global__ __launch_bounds__(256, 2)
void tones_fused(const int* __restrict__ widx,
                 const int* __restrict__ xidx,
                 const float* __restrict__ y,
                 const float* __restrict__ Wxh,
                 const float* __restrict__ bxh,
                 const float* __restrict__ Wwh,
                 const float* __restrict__ bwh,
                 const float* __restrict__ Wyh,
                 const float* __restrict__ byh,
                 const float* __restrict__ Wconv,
                 const float* __restrict__ bconv,
                 const float* __restrict__ Whl,
                 const float* __restrict__ bhl,
                 float* __restrict__ out)
{
    // LDS: 8448 + 4224 + 800 + 800 + 48 + 88 floats = 57,632 B -> 2 blocks/CU
    __shared__ __align__(16) float sWyhT[CDIM * NDIM];  // [j' = 2*d + c][n]
    __shared__ __align__(16) float sWhl[DDIM * NDIM];   // [d][n]
    __shared__ __align__(16) float sWxhT[HDIM * 50];    // [xi][n], pad 50
    __shared__ __align__(16) float sWwhT[HDIM * 50];    // [wi][n], pad 50
    __shared__ __align__(16) float sbinit[NDIM];        // b_xh + b_wh + b_yh
    __shared__ __align__(16) float sbhl[DDIM];

    const int tid = threadIdx.x;

    // --- Stage weights (transpose where useful) ---
    for (int e = tid; e < NDIM * CDIM; e += 256) {
        int n = e / CDIM;
        int j = e - n * CDIM;          // j = c*88 + d (reshape of [BT,C,D])
        int c = (j >= DDIM) ? 1 : 0;
        int d = j - c * DDIM;
        sWyhT[(2 * d + c) * NDIM + n] = Wyh[e];  // channel-interleaved rows
    }
    for (int e = tid; e < DDIM * NDIM; e += 256) sWhl[e] = Whl[e];
    for (int e = tid; e < NDIM * HDIM; e += 256) {
        int n = e >> 4, xi = e & 15;   // W_xh is [NDIM][HDIM] row-major
        sWxhT[xi * 50 + n] = Wxh[e];
        sWwhT[xi * 50 + n] = Wwh[e];
    }
    if (tid < NDIM) sbinit[tid] = bxh[tid] + bwh[tid] + byh[tid];
    if (tid < DDIM) sbhl[tid] = bhl[tid];

    // Conv weights: wave-uniform scalars (W_conv is [C=2][1][K=3])
    const float wc00 = Wconv[0], wc01 = Wconv[1], wc02 = Wconv[2];
    const float wc10 = Wconv[3], wc11 = Wconv[4], wc12 = Wconv[5];
    const float bc0 = bconv[0], bc1 = bconv[1];

    __syncthreads();

    const int token = blockIdx.x * 256 + tid;   // grid*block == NTOK exactly
    const int xi = xidx[token];
    const int wi = widx[token];

    // --- h init: one-hot gathers + summed biases ---
    float h[NDIM];
    {
        const float* px = &sWxhT[xi * 50];
        const float* pw = &sWwhT[wi * 50];
        #pragma unroll
        for (int n = 0; n < NDIM; n++) h[n] = sbinit[n] + px[n] + pw[n];
    }

    // --- Conv1d (1->2ch, k=3, pad=1) fused with h-stage GEMV, chunks of 8 tones ---
    const float* yr = y + (size_t)token * DDIM;   // 88 floats, 16B-aligned (352B rows)
    float carry = 0.0f;                           // y[d0-1], zero-pad at left edge
    #pragma unroll 1
    for (int k = 0; k < 11; k++) {
        float4 ca = *(const float4*)(yr + 8 * k);
        float4 cb = *(const float4*)(yr + 8 * k + 4);
        float v[10];
        v[0] = carry;
        v[1] = ca.x; v[2] = ca.y; v[3] = ca.z; v[4] = ca.w;
        v[5] = cb.x; v[6] = cb.y; v[7] = cb.z; v[8] = cb.w;
        v[9] = (k < 10) ? yr[8 * k + 8] : 0.0f;   // right edge pad
        carry = v[8];

        float yc[16];
        #pragma unroll
        for (int i = 0; i < 8; i++) {
            float a = v[i], m = v[i + 1], b = v[i + 2];
            float f0 = fmaf(wc02, b, fmaf(wc01, m, fmaf(wc00, a, bc0)));
            float f1 = fmaf(wc12, b, fmaf(wc11, m, fmaf(wc10, a, bc1)));
            yc[2 * i]     = fmaxf(f0, 0.0f);      // channel 0, tone 8k+i
            yc[2 * i + 1] = fmaxf(f1, 0.0f);      // channel 1, tone 8k+i
        }

        const float* wp = &sWyhT[(16 * k) * NDIM];
        #pragma unroll
        for (int jj = 0; jj < 16; jj++) {
            const float yv = yc[jj];
            const float* wr = wp + jj * NDIM;     // uniform address -> broadcast
            #pragma unroll
            for (int n = 0; n < NDIM; n++) h[n] = fmaf(yv, wr[n], h[n]);
        }
    }

    #pragma unroll
    for (int n = 0; n < NDIM; n++) h[n] = fmaxf(h[n], 0.0f);

    // --- Output layer: out[d] = b_hl[d] + sum_n h[n] * W_hl[d][n] ---
    float* orow = out + (size_t)token * DDIM;
    #pragma unroll 1
    for (int k = 0; k < 11; k++) {
        const float* bp = &sbhl[8 * k];
        const float* wl = &sWhl[(8 * k) * NDIM];
        float acc[8];
        #pragma unroll
        for (int i = 0; i < 8; i++) acc[i] = bp[i];
        #pragma unroll
        for (int i = 0; i < 8; i++) {
            const float* row = wl + i * NDIM;     // uniform address -> broadcast
            #pragma unroll
            for (int n = 0; n < NDIM; n++) acc[i] = fmaf(h[n], row[n], acc[i]);
        }
        float4 o0 = make_float4(acc[0], acc[1], acc[2], acc[3]);
        float4 o1 = make_float4(acc[4], acc[5], acc[6], acc[7]);
        *(float4*)(orow + 8 * k)     = o0;
        *(float4*)(orow + 8 * k + 4) = o1;
    }
}

extern "C" void kernel_launch(void* const* d_in, const int* in_sizes, int n_in,
                              void* d_out, int out_size, void* d_ws, size_t ws_size,
                              hipStream_t stream) {
    (void)in_sizes; (void)n_in; (void)out_size; (void)d_ws; (void)ws_size;
    tones_fused<<<dim3(NTOK / 256), dim3(256), 0, stream>>>(
        (const int*)d_in[0],                 // w indices
        (const int*)d_in[1],                 // x indices
        (const float*)d_in[2],               // y
        (const float*)d_in[3],  (const float*)d_in[4],   // W_xh, b_xh
        (const float*)d_in[5],  (const float*)d_in[6],   // W_wh, b_wh
        (const float*)d_in[7],  (const float*)d_in[8],   // W_yh, b_yh
        (const float*)d_in[9],  (const float*)d_in[10],  // W_conv, b_conv
        (const float*)d_in[11], (const float*)d_in[12],  // W_hl, b_hl
        (float*)d_out);
}

// Round 3
// 154.302 us; speedup vs baseline: 1.2870x; 1.2870x over previous
//
#include <hip/hip_runtime.h>
#include <stdint.h>

// B=256, T=512; all float tensors are f32. Two MFMA GEMMs with one-hots and
// biases folded in as extra K-rows.
#define NTOK (256 * 512)
#define TPB 256
#define TOKENS_PER_BLOCK 256
#define TILES_PER_WAVE 4      // 4 waves * 4 tiles * 16 tokens = 256 tokens/block

typedef short bf16x8 __attribute__((ext_vector_type(8)));
typedef float f32x4 __attribute__((ext_vector_type(4)));
typedef unsigned short u16;
typedef unsigned int u32;

// u16-unit offsets inside sAll (total 31520 u16 = 63040 B -> 2 blocks/CU)
// B1: [K=224 -> 28 chunks][N=48] bf16, chunk-major, 49-pad: 28*49*8 = 10976
// B2: [K=64  ->  8 chunks][N=96] bf16, 97-pad:               8*97*8 =  6208
// per-wave A staging: 28 chunks * 16 rows * 8 = 3584 (H for GEMM2 overlaps
// chunks 0..7 of the same region; per-wave LDS ops are in-order, so reuse is
// safe without barriers).
#define OFF_B1 0
#define OFF_B2 10976
#define OFF_WAVE 17184
#define WAVE_SZ 3584

__device__ __forceinline__ u16 f2bf(float f) {
    u32 u = __float_as_uint(f);
    return (u16)((u + 0x7fffu + ((u >> 16) & 1u)) >> 16);  // rne
}

__global__ __launch_bounds__(256, 2)
void tones_mfma(const int* __restrict__ widx, const int* __restrict__ xidx,
                const float* __restrict__ y,
                const float* __restrict__ Wxh, const float* __restrict__ bxh,
                const float* __restrict__ Wwh, const float* __restrict__ bwh,
                const float* __restrict__ Wyh, const float* __restrict__ byh,
                const float* __restrict__ Wconv, const float* __restrict__ bconv,
                const float* __restrict__ Whl, const float* __restrict__ bhl,
                float* __restrict__ out)
{
    __shared__ __align__(16) u16 sAll[31520];
    const int tid = threadIdx.x;

    // ---- stage B1 = [Wyh(ch-interleaved) ; WxhT ; WwhT ; bias ; 0] as bf16 ----
    for (int idx = tid; idx < 224 * 48; idx += TPB) {
        int k = idx / 48, n = idx - 48 * k;
        float v;
        if (k < 176)       v = Wyh[n * 176 + (k & 1) * 88 + (k >> 1)];  // k=2d+c -> j=c*88+d
        else if (k < 192)  v = Wxh[n * 16 + (k - 176)];
        else if (k < 208)  v = Wwh[n * 16 + (k - 192)];
        else if (k == 208) v = bxh[n] + bwh[n] + byh[n];
        else               v = 0.0f;
        sAll[OFF_B1 + ((k >> 3) * 49 + n) * 8 + (k & 7)] = f2bf(v);
    }
    // ---- stage B2 = [WhlT ; bhl ; 0], N padded 88->96 ----
    for (int idx = tid; idx < 64 * 96; idx += TPB) {
        int k = idx / 96, dd = idx - 96 * k;
        float v = 0.0f;
        if (dd < 88) {
            if (k < 48)       v = Whl[dd * 48 + k];
            else if (k == 48) v = bhl[dd];
        }
        sAll[OFF_B2 + ((k >> 3) * 97 + dd) * 8 + (k & 7)] = f2bf(v);
    }
    const float wc00 = Wconv[0], wc01 = Wconv[1], wc02 = Wconv[2];
    const float wc10 = Wconv[3], wc11 = Wconv[4], wc12 = Wconv[5];
    const float bc0 = bconv[0], bc1 = bconv[1];
    __syncthreads();   // only barrier in the kernel

    const int wave = tid >> 6, lane = tid & 63;
    const int q = lane >> 4, c = lane & 15;   // MFMA quad / 16-index
    u16* sW = &sAll[OFF_WAVE + wave * WAVE_SZ];

    #pragma unroll 1
    for (int t = 0; t < TILES_PER_WAVE; t++) {
        const int tb = blockIdx.x * TOKENS_PER_BLOCK + wave * (TILES_PER_WAVE * 16) + t * 16;

        // ---- conv(1->2ch,k=3,pad=1) + relu -> A-fragment-ordered yc in LDS ----
        // tile = 16 tokens * 88 floats = 1408 contiguous floats; each float4 is
        // within one row (88 = 22*4), so neighbors are row-local scalar reloads.
        const float* yrow = y + (size_t)tb * 88;
        #pragma unroll
        for (int w = 0; w < 6; w++) {
            int flat = w * 256 + 4 * lane;
            if (flat < 1408) {
                float4 v = *(const float4*)(yrow + flat);
                int m = flat / 88;
                int d0 = flat - 88 * m;
                float L  = (d0 == 0)  ? 0.0f : yrow[flat - 1];  // L1 hit
                float Rv = (d0 == 84) ? 0.0f : yrow[flat + 4];
                float a0 = L, a1 = v.x, a2 = v.y, a3 = v.z, a4 = v.w, a5 = Rv;
                float c00 = fmaf(wc00, a0, fmaf(wc01, a1, fmaf(wc02, a2, bc0)));
                float c01 = fmaf(wc00, a1, fmaf(wc01, a2, fmaf(wc02, a3, bc0)));
                float c02 = fmaf(wc00, a2, fmaf(wc01, a3, fmaf(wc02, a4, bc0)));
                float c03 = fmaf(wc00, a3, fmaf(wc01, a4, fmaf(wc02, a5, bc0)));
                float c10 = fmaf(wc10, a0, fmaf(wc11, a1, fmaf(wc12, a2, bc1)));
                float c11 = fmaf(wc10, a1, fmaf(wc11, a2, fmaf(wc12, a3, bc1)));
                float c12 = fmaf(wc10, a2, fmaf(wc11, a3, fmaf(wc12, a4, bc1)));
                float c13 = fmaf(wc10, a3, fmaf(wc11, a4, fmaf(wc12, a5, bc1)));
                uint4 pk;
                pk.x = (u32)f2bf(fmaxf(c00, 0.f)) | ((u32)f2bf(fmaxf(c10, 0.f)) << 16);
                pk.y = (u32)f2bf(fmaxf(c01, 0.f)) | ((u32)f2bf(fmaxf(c11, 0.f)) << 16);
                pk.z = (u32)f2bf(fmaxf(c02, 0.f)) | ((u32)f2bf(fmaxf(c12, 0.f)) << 16);
                pk.w = (u32)f2bf(fmaxf(c03, 0.f)) | ((u32)f2bf(fmaxf(c13, 0.f)) << 16);
                // element (row m, k = 2*d0 .. 2*d0+7) -> chunk d0>>2
                *(uint4*)(sW + ((d0 >> 2) * 16 + m) * 8) = pk;
            }
        }
        // ---- one-hot K-rows (chunks 22..25: x then w) + bias/zero (26,27) ----
        {
            int hv = ((lane < 32) ? xidx : widx)[tb + c];
            int q2 = q & 1;
            u32 dw0 = 0, dw1 = 0, dw2 = 0, dw3 = 0;
            if ((hv >> 3) == q2) {
                u32 bit = 0x3F80u << (16 * (hv & 1));
                int sl = (hv & 7) >> 1;
                dw0 = (sl == 0) ? bit : 0; dw1 = (sl == 1) ? bit : 0;
                dw2 = (sl == 2) ? bit : 0; dw3 = (sl == 3) ? bit : 0;
            }
            *(uint4*)(sW + ((22 + q) * 16 + c) * 8) = make_uint4(dw0, dw1, dw2, dw3);
            if (lane < 32) {   // chunk 26: bias-one at k=208; chunk 27: zeros
                uint4 z = make_uint4((lane < 16) ? 0x3F80u : 0u, 0, 0, 0);
                *(uint4*)(sW + ((26 + q) * 16 + c) * 8) = z;
            }
        }
        // ---- GEMM1: h[16 x 48] = A[16 x 224] * B1[224 x 48] ----
        f32x4 acc0 = {0,0,0,0}, acc1 = {0,0,0,0}, acc2 = {0,0,0,0};
        #pragma unroll
        for (int ks = 0; ks < 7; ks++) {
            bf16x8 a = *(const bf16x8*)(sW + ((ks * 4 + q) * 16 + c) * 8);
            bf16x8 b0 = *(const bf16x8*)(&sAll[OFF_B1 + ((ks * 4 + q) * 49 + c) * 8]);
            acc0 = __builtin_amdgcn_mfma_f32_16x16x32_bf16(a, b0, acc0, 0, 0, 0);
            bf16x8 b1 = *(const bf16x8*)(&sAll[OFF_B1 + ((ks * 4 + q) * 49 + 16 + c) * 8]);
            acc1 = __builtin_amdgcn_mfma_f32_16x16x32_bf16(a, b1, acc1, 0, 0, 0);
            bf16x8 b2 = *(const bf16x8*)(&sAll[OFF_B1 + ((ks * 4 + q) * 49 + 32 + c) * 8]);
            acc2 = __builtin_amdgcn_mfma_f32_16x16x32_bf16(a, b2, acc2, 0, 0, 0);
        }
        // ---- epilogue1: relu -> bf16 H in A-frag order (reuses chunks 0..7) ----
        if (lane < 32) {   // chunk 6: bias-one at k2=48; chunk 7: zeros
            uint4 hz = make_uint4((lane < 16) ? 0x3F80u : 0u, 0, 0, 0);
            *(uint4*)(sW + ((6 + q) * 16 + c) * 8) = hz;
        }
        #pragma unroll
        for (int r = 0; r < 4; r++) {
            int row = q * 4 + r;   // D row = token index
            sW[((0 * 2 + (c >> 3)) * 16 + row) * 8 + (c & 7)] = f2bf(fmaxf(acc0[r], 0.f));
            sW[((1 * 2 + (c >> 3)) * 16 + row) * 8 + (c & 7)] = f2bf(fmaxf(acc1[r], 0.f));
            sW[((2 * 2 + (c >> 3)) * 16 + row) * 8 + (c & 7)] = f2bf(fmaxf(acc2[r], 0.f));
        }
        // ---- GEMM2: out[16 x 88] = H[16 x 64] * B2[64 x 96] ----
        f32x4 o0 = {0,0,0,0}, o1 = {0,0,0,0}, o2 = {0,0,0,0};
        f32x4 o3 = {0,0,0,0}, o4 = {0,0,0,0}, o5 = {0,0,0,0};
        #pragma unroll
        for (int ks = 0; ks < 2; ks++) {
            bf16x8 a2 = *(const bf16x8*)(sW + ((ks * 4 + q) * 16 + c) * 8);
            bf16x8 b;
            b = *(const bf16x8*)(&sAll[OFF_B2 + ((ks * 4 + q) * 97 +  0 + c) * 8]);
            o0 = __builtin_amdgcn_mfma_f32_16x16x32_bf16(a2, b, o0, 0, 0, 0);
            b = *(const bf16x8*)(&sAll[OFF_B2 + ((ks * 4 + q) * 97 + 16 + c) * 8]);
            o1 = __builtin_amdgcn_mfma_f32_16x16x32_bf16(a2, b, o1, 0, 0, 0);
            b = *(const bf16x8*)(&sAll[OFF_B2 + ((ks * 4 + q) * 97 + 32 + c) * 8]);
            o2 = __builtin_amdgcn_mfma_f32_16x16x32_bf16(a2, b, o2, 0, 0, 0);
            b = *(const bf16x8*)(&sAll[OFF_B2 + ((ks * 4 + q) * 97 + 48 + c) * 8]);
            o3 = __builtin_amdgcn_mfma_f32_16x16x32_bf16(a2, b, o3, 0, 0, 0);
            b = *(const bf16x8*)(&sAll[OFF_B2 + ((ks * 4 + q) * 97 + 64 + c) * 8]);
            o4 = __builtin_amdgcn_mfma_f32_16x16x32_bf16(a2, b, o4, 0, 0, 0);
            b = *(const bf16x8*)(&sAll[OFF_B2 + ((ks * 4 + q) * 97 + 80 + c) * 8]);
            o5 = __builtin_amdgcn_mfma_f32_16x16x32_bf16(a2, b, o5, 0, 0, 0);
        }
        // ---- store: D row = token (q*4+r), col = d = nt*16 + c ----
        float* orow = out + (size_t)(tb + q * 4) * 88;
        #pragma unroll
        for (int r = 0; r < 4; r++) {
            orow[r * 88 +  0 + c] = o0[r];
            orow[r * 88 + 16 + c] = o1[r];
            orow[r * 88 + 32 + c] = o2[r];
            orow[r * 88 + 48 + c] = o3[r];
            orow[r * 88 + 64 + c] = o4[r];
            if (c < 8) orow[r * 88 + 80 + c] = o5[r];
        }
    }
}

extern "C" void kernel_launch(void* const* d_in, const int* in_sizes, int n_in,
                              void* d_out, int out_size, void* d_ws, size_t ws_size,
                              hipStream_t stream) {
    (void)in_sizes; (void)n_in; (void)out_size; (void)d_ws; (void)ws_size;
    tones_mfma<<<dim3(NTOK / TOKENS_PER_BLOCK), dim3(TPB), 0, stream>>>(
        (const int*)d_in[0], (const int*)d_in[1], (const float*)d_in[2],
        (const float*)d_in[3],  (const float*)d_in[4],
        (const float*)d_in[5],  (const float*)d_in[6],
        (const float*)d_in[7],  (const float*)d_in[8],
        (const float*)d_in[9],  (const float*)d_in[10],
        (const float*)d_in[11], (const float*)d_in[12],
        (float*)d_out);
}